// Round 5
// baseline (300.249 us; speedup 1.0000x reference)
//
#include <hip/hip_runtime.h>
#include <cmath>

#define SRATE 16000
#define WIN   400
#define HOP   160
#define NFFT  512
#define NBIN  257          // NFFT/2+1
#define NMELS 40
#define NMFCC 13
#define BB    64
#define LL    160000
#define NF    998          // (L-WIN)/HOP + 1

#define PI_D 3.14159265358979323846

// workspace layout (floats)
#define WS_WINDOW 0                    // 400
#define WS_W1     400                  // 64 x float2 = 128   (W_256^l)
#define WS_STW    528                  // 6 stages x 64 x float2 = 768
#define WS_UNTC   1296                 // 64 x float4 = 256 (permuted untangle cos)
#define WS_UNTS   1552                 // 64 x float4 = 256 (permuted untangle -sin)
#define WS_MELT   1808                 // 4 slots x 64 x float4 = 1024 (permuted mel scatter)
#define WS_MT     2832                 // 40 x 39 = 1560 (fused DCT+delta, [n][i])
#define WS_TOTAL  (WS_MT + 1560)       // 4392 floats

__device__ __forceinline__ int brev6(int v) { return (int)(__brev((unsigned)v) >> 26); }

// ---------------------------------------------------------------------------
// Init kernel: recompute constant tables every launch (ws is re-poisoned).
// ---------------------------------------------------------------------------
__global__ void init_tables(float* __restrict__ ws) {
    __shared__ double bins[NMELS + 2];
    const int tid = threadIdx.x;

    // Hamming window (periodic)
    for (int i = tid; i < WIN; i += 256)
        ws[WS_WINDOW + i] = (float)(0.54 - 0.46 * cos(2.0 * PI_D * (double)i / (double)WIN));

    // W1[l] = e^{-2*pi*i*l/256}
    if (tid < 64) {
        double ang = -2.0 * PI_D * (double)tid / 256.0;
        ws[WS_W1 + 2 * tid]     = (float)cos(ang);
        ws[WS_W1 + 2 * tid + 1] = (float)sin(ang);
    }

    // cross-lane DIF stage twiddles: stage st (h = 32>>st), lane l:
    //   (l & h) ? e^{-i*pi*(l&(h-1))/h} : 1
    for (int i = tid; i < 6 * 64; i += 256) {
        int st = i >> 6, lane = i & 63;
        int h = 32 >> st;
        double cr = 1.0, ci = 0.0;
        if (lane & h) {
            double ang = -PI_D * (double)(lane & (h - 1)) / (double)h;
            cr = cos(ang); ci = sin(ang);
        }
        ws[WS_STW + st * 128 + 2 * lane]     = (float)cr;
        ws[WS_STW + st * 128 + 2 * lane + 1] = (float)ci;
    }

    // permuted untangle twiddles: lane l slot k1 -> m = k1 + 4*bitrev6(l)
    if (tid < 256) {
        int lane = tid >> 2, k1 = tid & 3;
        int m = k1 + 4 * brev6(lane);
        double ang = 2.0 * PI_D * (double)m / 512.0;
        ws[WS_UNTC + 4 * lane + k1] = (float)cos(ang);
        ws[WS_UNTS + 4 * lane + k1] = (float)(-sin(ang));
    }

    // mel bin edges
    if (tid < NMELS + 2) {
        double high_mel = 2595.0 * log10(1.0 + ((double)SRATE / 2.0) / 700.0);
        double step = high_mel / (double)(NMELS + 1);
        double mel = (tid == NMELS + 1) ? high_mel : (double)tid * step;
        double hz = 700.0 * (pow(10.0, mel / 2595.0) - 1.0);
        bins[tid] = floor((double)(NFFT + 1) * hz / (double)SRATE);
    }
    __syncthreads();

    // permuted mel scatter table: slot-major [k1][lane] float4
    if (tid < 256) {
        int k1 = tid >> 6, lane = tid & 63;
        int k = k1 + 4 * brev6(lane);
        int r1 = 0;
        while (r1 < NMELS + 1 &&
               !((double)k >= bins[r1] && (double)k < bins[r1 + 1])) r1++;
        if (r1 > NMELS) r1 = NMELS;
        double lo = bins[r1], hi = bins[r1 + 1];
        double den = (hi > lo) ? (hi - lo) : 1.0;
        float* e = ws + WS_MELT + k1 * 256 + lane * 4;
        e[0] = (float)(((double)k - lo) / den);   // rising  -> row r1   (melw[1+r1])
        e[1] = (float)((hi - (double)k) / den);   // falling -> row r1-1 (melw[r1])
        e[2] = (float)r1;
        e[3] = 0.0f;
    }

    // fused DCT + delta matrix, [n][i] layout: MT[n*39 + i]
    for (int t = tid; t < 40 * 39; t += 256) {
        int n = t / 39, i = t % 39;
        auto dctf = [&](int c) -> double {
            if (c < 0 || c > 39) return 0.0;
            double sc = (c == 0) ? sqrt(1.0 / 40.0) : sqrt(2.0 / 40.0);
            return sc * cos(PI_D * (double)c * (2.0 * n + 1.0) / 80.0);
        };
        auto d1f = [&](int c) -> double {
            if (c < 1 || c > 38) return 0.0;
            return 0.5 * (dctf(c + 1) - dctf(c - 1));
        };
        double v;
        if (i < 13)       v = dctf(i);
        else if (i < 26)  v = d1f(i - 13);
        else { int c = i - 26; v = (c >= 1 && c <= 38) ? 0.5 * (d1f(c + 1) - d1f(c - 1)) : 0.0; }
        ws[WS_MT + t] = (float)v;
    }
}

// ---------------------------------------------------------------------------
// Main kernel: one WAVE per TWO adjacent frames (float2 SoA: .x=f0, .y=f1).
// Register FFT (4-step 4x64) via shuffles; tables shared across both frames.
// ---------------------------------------------------------------------------
#define NTHREADS 256

__device__ __forceinline__ float2 shflx2(float2 v, int m) {
    return make_float2(__shfl_xor(v.x, m, 64), __shfl_xor(v.y, m, 64));
}
__device__ __forceinline__ float2 shfl2(float2 v, int src) {
    return make_float2(__shfl(v.x, src, 64), __shfl(v.y, src, 64));
}

__global__ __launch_bounds__(NTHREADS, 4) void mfcc_kernel(
    const float* __restrict__ x, const float* __restrict__ ws,
    float* __restrict__ out) {

    __shared__ float melw_all[4][2][48];
    __shared__ __align__(16) float lm_all[4][2][44];

    const int tid = threadIdx.x;
    const int w = tid >> 6;
    const int l = tid & 63;
    const int gw = blockIdx.x * 4 + w;       // global wave id
    const int fid0 = 2 * gw;
    const int fid1 = fid0 + 1;
    const int b0 = fid0 / NF, f0 = fid0 - b0 * NF;
    const int b1 = fid1 / NF, f1 = fid1 - b1 * NF;
    const float* xp0 = x + (size_t)b0 * LL;
    const float* xp1 = x + (size_t)b1 * LL;
    const int st0 = f0 * HOP, st1 = f1 * HOP;

    float* melw0 = melw_all[w][0];
    float* melw1 = melw_all[w][1];

    if (l < 48) { melw0[l] = 0.0f; melw1[l] = 0.0f; }

    // ---- prefetch shared tables (held in registers across the FFT) ----
    const float2 w1  = *(const float2*)(ws + WS_W1 + 2 * l);
    const float2 tws0 = *(const float2*)(ws + WS_STW + 0 * 128 + 2 * l);
    const float2 tws1 = *(const float2*)(ws + WS_STW + 1 * 128 + 2 * l);
    const float2 tws2 = *(const float2*)(ws + WS_STW + 2 * 128 + 2 * l);
    const float2 tws3 = *(const float2*)(ws + WS_STW + 3 * 128 + 2 * l);
    const float2 tws4 = *(const float2*)(ws + WS_STW + 4 * 128 + 2 * l);

    // ---- pack both frames: lane l slot a holds z[l + 64a] ----
    float2 z0r, z0i, z1r, z1i, z2r, z2i, z3r, z3i;
#define PACK(A, ZR, ZI)                                               \
    {                                                                 \
        float2 r = make_float2(0.f, 0.f), im = make_float2(0.f, 0.f); \
        int n2 = 2 * l + 128 * (A);                                   \
        if (n2 < WIN) {                                               \
            float2 wv = *(const float2*)(ws + WS_WINDOW + n2);        \
            int g0 = st0 + n2;                                        \
            float2 xv0 = *(const float2*)(xp0 + g0);                  \
            float xm0 = (g0 > 0) ? xp0[g0 - 1] : 0.0f;                \
            int g1 = st1 + n2;                                        \
            float2 xv1 = *(const float2*)(xp1 + g1);                  \
            float xm1 = (g1 > 0) ? xp1[g1 - 1] : 0.0f;                \
            r.x  = (xv0.x - 0.97f * xm0)   * wv.x;                    \
            im.x = (xv0.y - 0.97f * xv0.x) * wv.y;                    \
            r.y  = (xv1.x - 0.97f * xm1)   * wv.x;                    \
            im.y = (xv1.y - 0.97f * xv1.x) * wv.y;                    \
        }                                                             \
        ZR = r; ZI = im;                                              \
    }
    PACK(0, z0r, z0i)
    PACK(1, z1r, z1i)
    PACK(2, z2r, z2i)
    PACK(3, z3r, z3i)
#undef PACK

    // ---- in-register radix-4 over n1 (W4^1 = -i), componentwise ----
    {
        float2 t0r = make_float2(z0r.x + z2r.x, z0r.y + z2r.y);
        float2 t0i = make_float2(z0i.x + z2i.x, z0i.y + z2i.y);
        float2 t1r = make_float2(z0r.x - z2r.x, z0r.y - z2r.y);
        float2 t1i = make_float2(z0i.x - z2i.x, z0i.y - z2i.y);
        float2 t2r = make_float2(z1r.x + z3r.x, z1r.y + z3r.y);
        float2 t2i = make_float2(z1i.x + z3i.x, z1i.y + z3i.y);
        float2 t3r = make_float2(z1r.x - z3r.x, z1r.y - z3r.y);
        float2 t3i = make_float2(z1i.x - z3i.x, z1i.y - z3i.y);
        z0r = make_float2(t0r.x + t2r.x, t0r.y + t2r.y);
        z0i = make_float2(t0i.x + t2i.x, t0i.y + t2i.y);
        z1r = make_float2(t1r.x + t3i.x, t1r.y + t3i.y);
        z1i = make_float2(t1i.x - t3r.x, t1i.y - t3r.y);
        z2r = make_float2(t0r.x - t2r.x, t0r.y - t2r.y);
        z2i = make_float2(t0i.x - t2i.x, t0i.y - t2i.y);
        z3r = make_float2(t1r.x - t3i.x, t1r.y - t3i.y);
        z3i = make_float2(t1i.x + t3r.x, t1i.y + t3r.y);
    }

    // ---- twiddle by W_256^{l*k1} (scalar twiddles, both frames) ----
#define CMULS(ZR, ZI, WR, WI)                                         \
    {                                                                 \
        float2 tr = make_float2(ZR.x * (WR) - ZI.x * (WI),            \
                                ZR.y * (WR) - ZI.y * (WI));           \
        ZI = make_float2(ZR.x * (WI) + ZI.x * (WR),                   \
                         ZR.y * (WI) + ZI.y * (WR));                  \
        ZR = tr;                                                      \
    }
    {
        float w2r = w1.x * w1.x - w1.y * w1.y, w2i = 2.0f * w1.x * w1.y;
        float w3r = w2r * w1.x - w2i * w1.y,   w3i = w2r * w1.y + w2i * w1.x;
        CMULS(z1r, z1i, w1.x, w1.y)
        CMULS(z2r, z2i, w2r,  w2i)
        CMULS(z3r, z3i, w3r,  w3i)
    }

    // ---- 6 cross-lane DIF stages via shfl_xor (output bit-reversed) ----
#define BFLY(ZR, ZI, H, TWR, TWI, SGN, LAST)                          \
    {                                                                 \
        float2 pr = shflx2(ZR, (H));                                  \
        float2 pi = shflx2(ZI, (H));                                  \
        float2 ar = make_float2(fmaf((SGN), ZR.x, pr.x),              \
                                fmaf((SGN), ZR.y, pr.y));             \
        float2 ai = make_float2(fmaf((SGN), ZI.x, pi.x),              \
                                fmaf((SGN), ZI.y, pi.y));             \
        if (LAST) { ZR = ar; ZI = ai; }                               \
        else {                                                        \
            ZR = make_float2(ar.x * (TWR) - ai.x * (TWI),             \
                             ar.y * (TWR) - ai.y * (TWI));            \
            ZI = make_float2(ar.x * (TWI) + ai.x * (TWR),             \
                             ar.y * (TWI) + ai.y * (TWR));            \
        }                                                             \
    }
#define CLSTAGE(H, TW, LAST)                                          \
    {                                                                 \
        float sgn = (l & (H)) ? -1.0f : 1.0f;                         \
        BFLY(z0r, z0i, H, TW.x, TW.y, sgn, LAST)                      \
        BFLY(z1r, z1i, H, TW.x, TW.y, sgn, LAST)                      \
        BFLY(z2r, z2i, H, TW.x, TW.y, sgn, LAST)                      \
        BFLY(z3r, z3i, H, TW.x, TW.y, sgn, LAST)                      \
    }
    CLSTAGE(32, tws0, false)
    CLSTAGE(16, tws1, false)
    CLSTAGE(8,  tws2, false)
    CLSTAGE(4,  tws3, false)
    CLSTAGE(2,  tws4, false)
    CLSTAGE(1,  tws4, true)     // W_2^0 = 1: twiddle unused
#undef CLSTAGE
#undef BFLY
#undef CMULS

    // lane l slot k1 now holds Z[m], m = k1 + 4*bitrev6(l)

    // ---- rfft untangle: partner Z[(256-m)&255]; 63-l == l^63 ----
    float2 p1r = shflx2(z3r, 63), p1i = shflx2(z3i, 63);
    float2 p2r = shflx2(z2r, 63), p2i = shflx2(z2i, 63);
    float2 p3r = shflx2(z1r, 63), p3i = shflx2(z1i, 63);
    int q = brev6((64 - brev6(l)) & 63);
    float2 p0r = shfl2(z0r, q), p0i = shfl2(z0i, q);

    float4 uc = *(const float4*)(ws + WS_UNTC + 4 * l);
    float4 us = *(const float4*)(ws + WS_UNTS + 4 * l);

    float2 mg0, mg1, mg2, mg3;
#define UNT(A, Bv, C, D, WR, WI, MG)                                  \
    {                                                                 \
        float2 Pr = make_float2(A.x + C.x, A.y + C.y);                \
        float2 Pi = make_float2(Bv.x - D.x, Bv.y - D.y);              \
        float2 Qr = make_float2(A.x - C.x, A.y - C.y);                \
        float2 Qi = make_float2(Bv.x + D.x, Bv.y + D.y);              \
        float Xr0 = 0.5f * (Pr.x + (WI) * Qr.x + (WR) * Qi.x);        \
        float Xi0 = 0.5f * (Pi.x + (WI) * Qi.x - (WR) * Qr.x);        \
        float Xr1 = 0.5f * (Pr.y + (WI) * Qr.y + (WR) * Qi.y);        \
        float Xi1 = 0.5f * (Pi.y + (WI) * Qi.y - (WR) * Qr.y);        \
        MG = make_float2(sqrtf(Xr0 * Xr0 + Xi0 * Xi0),                \
                         sqrtf(Xr1 * Xr1 + Xi1 * Xi1));               \
    }
    UNT(z0r, z0i, p0r, p0i, uc.x, us.x, mg0)
    UNT(z1r, z1i, p1r, p1i, uc.y, us.y, mg1)
    UNT(z2r, z2i, p2r, p2i, uc.z, us.z, mg2)
    UNT(z3r, z3i, p3r, p3i, uc.w, us.w, mg3)
#undef UNT

    // ---- mel scatter (shared table), per-wave-per-frame LDS atomics ----
    {
        const float4* mlt = (const float4*)(ws + WS_MELT);
        float4 t0 = mlt[0 * 64 + l];
        float4 t1 = mlt[1 * 64 + l];
        float4 t2 = mlt[2 * 64 + l];
        float4 t3 = mlt[3 * 64 + l];
        int r;
        r = (int)t0.z;
        atomicAdd(&melw0[1 + r], t0.x * mg0.x); atomicAdd(&melw0[r], t0.y * mg0.x);
        atomicAdd(&melw1[1 + r], t0.x * mg0.y); atomicAdd(&melw1[r], t0.y * mg0.y);
        r = (int)t1.z;
        atomicAdd(&melw0[1 + r], t1.x * mg1.x); atomicAdd(&melw0[r], t1.y * mg1.x);
        atomicAdd(&melw1[1 + r], t1.x * mg1.y); atomicAdd(&melw1[r], t1.y * mg1.y);
        r = (int)t2.z;
        atomicAdd(&melw0[1 + r], t2.x * mg2.x); atomicAdd(&melw0[r], t2.y * mg2.x);
        atomicAdd(&melw1[1 + r], t2.x * mg2.y); atomicAdd(&melw1[r], t2.y * mg2.y);
        r = (int)t3.z;
        atomicAdd(&melw0[1 + r], t3.x * mg3.x); atomicAdd(&melw0[r], t3.y * mg3.x);
        atomicAdd(&melw1[1 + r], t3.x * mg3.y); atomicAdd(&melw1[r], t3.y * mg3.y);
    }
    __builtin_amdgcn_wave_barrier();

    // ---- log, stage lm into per-wave LDS for b128 broadcast ----
    float* lm0 = lm_all[w][0];
    float* lm1 = lm_all[w][1];
    if (l < NMELS) {
        lm0[l] = logf(melw0[1 + l] + 1e-20f);
        lm1[l] = logf(melw1[1 + l] + 1e-20f);
    }
    __builtin_amdgcn_wave_barrier();

    // ---- fused DCT+deltas matvec, both frames ----
    float2 acc = make_float2(0.f, 0.f);
    const float* mt = ws + WS_MT;
    int ii = (l < 39) ? l : 0;
    #pragma unroll
    for (int g = 0; g < 10; g++) {
        float4 a4 = *(const float4*)(lm0 + 4 * g);   // broadcast reads
        float4 b4 = *(const float4*)(lm1 + 4 * g);
        float m0 = mt[(4 * g + 0) * 39 + ii];
        float m1 = mt[(4 * g + 1) * 39 + ii];
        float m2 = mt[(4 * g + 2) * 39 + ii];
        float m3 = mt[(4 * g + 3) * 39 + ii];
        acc.x = fmaf(m0, a4.x, acc.x); acc.y = fmaf(m0, b4.x, acc.y);
        acc.x = fmaf(m1, a4.y, acc.x); acc.y = fmaf(m1, b4.y, acc.y);
        acc.x = fmaf(m2, a4.z, acc.x); acc.y = fmaf(m2, b4.z, acc.y);
        acc.x = fmaf(m3, a4.w, acc.x); acc.y = fmaf(m3, b4.w, acc.y);
    }
    if (l < 39) {
        out[(size_t)fid0 * 39 + l] = acc.x;
        out[(size_t)fid1 * 39 + l] = acc.y;
    }
}

// ---------------------------------------------------------------------------
extern "C" void kernel_launch(void* const* d_in, const int* in_sizes, int n_in,
                              void* d_out, int out_size, void* d_ws, size_t ws_size,
                              hipStream_t stream) {
    const float* x = (const float*)d_in[0];
    float* ws = (float*)d_ws;
    float* out = (float*)d_out;

    init_tables<<<1, 256, 0, stream>>>(ws);
    mfcc_kernel<<<(BB * NF) / 8, NTHREADS, 0, stream>>>(x, ws, out);
}

// Round 6
// 141.234 us; speedup vs baseline: 2.1259x; 2.1259x over previous
//
#include <hip/hip_runtime.h>
#include <cmath>

#define SRATE 16000
#define WIN   400
#define HOP   160
#define NFFT  512
#define NBIN  257          // NFFT/2+1
#define NMELS 40
#define NMFCC 13
#define BB    64
#define LL    160000
#define NF    998          // (L-WIN)/HOP + 1

#define PI_D 3.14159265358979323846

// workspace layout (floats)
#define WS_WINDOW 0                    // 400
#define WS_W1     400                  // 64 x float2 = 128   (W_256^l)
#define WS_STW    528                  // 6 stages x 64 x float2 = 768
#define WS_UNTC   1296                 // 64 x float4 = 256 (permuted untangle cos)
#define WS_UNTS   1552                 // 64 x float4 = 256 (permuted untangle -sin)
#define WS_SM     1808                 // 64 (filter support start bin)
#define WS_FBW    1872                 // 9 jc x 64 lanes x 4 = 2304 (mel weights)
#define WS_MT     4176                 // 40 x 39 = 1560 (fused DCT+delta, [n][i])
#define WS_TOTAL  (WS_MT + 1560)       // 5736 floats

#define LOFF(m) ((m) + ((m) >> 3))     // padded LDS mag indexing (max 295)

__device__ __forceinline__ int brev6(int v) { return (int)(__brev((unsigned)v) >> 26); }

// ---------------------------------------------------------------------------
// Init kernel (8 blocks): recompute constant tables every launch.
// ---------------------------------------------------------------------------
__global__ void init_tables(float* __restrict__ ws) {
    __shared__ double bins[NMELS + 2];
    const int tid = threadIdx.x;
    const int gid = blockIdx.x * 256 + tid;
    const int gstr = gridDim.x * 256;

    // mel bin edges (every block computes its own copy)
    if (tid < NMELS + 2) {
        double high_mel = 2595.0 * log10(1.0 + ((double)SRATE / 2.0) / 700.0);
        double step = high_mel / (double)(NMELS + 1);
        double mel = (tid == NMELS + 1) ? high_mel : (double)tid * step;
        double hz = 700.0 * (pow(10.0, mel / 2595.0) - 1.0);
        bins[tid] = floor((double)(NFFT + 1) * hz / (double)SRATE);
    }
    __syncthreads();

    // Hamming window (periodic)
    for (int i = gid; i < WIN; i += gstr)
        ws[WS_WINDOW + i] = (float)(0.54 - 0.46 * cos(2.0 * PI_D * (double)i / (double)WIN));

    // W1[l] = e^{-2*pi*i*l/256}
    if (gid < 64) {
        double ang = -2.0 * PI_D * (double)gid / 256.0;
        ws[WS_W1 + 2 * gid]     = (float)cos(ang);
        ws[WS_W1 + 2 * gid + 1] = (float)sin(ang);
    }

    // cross-lane DIF stage twiddles
    for (int i = gid; i < 6 * 64; i += gstr) {
        int st = i >> 6, lane = i & 63;
        int h = 32 >> st;
        double cr = 1.0, ci = 0.0;
        if (lane & h) {
            double ang = -PI_D * (double)(lane & (h - 1)) / (double)h;
            cr = cos(ang); ci = sin(ang);
        }
        ws[WS_STW + st * 128 + 2 * lane]     = (float)cr;
        ws[WS_STW + st * 128 + 2 * lane + 1] = (float)ci;
    }

    // permuted untangle twiddles: lane l slot k1 -> m = k1 + 4*bitrev6(l)
    for (int i = gid; i < 256; i += gstr) {
        int lane = i >> 2, k1 = i & 3;
        int m = k1 + 4 * brev6(lane);
        double ang = 2.0 * PI_D * (double)m / 512.0;
        ws[WS_UNTC + 4 * lane + k1] = (float)cos(ang);
        ws[WS_UNTS + 4 * lane + k1] = (float)(-sin(ang));
    }

    // mel support start bins
    for (int i = gid; i < 64; i += gstr)
        ws[WS_SM + i] = (i < NMELS) ? (float)bins[i] : 0.0f;

    // mel weights, transposed for coalesced float4 loads:
    // FBW[jc*256 + r*4 + d] = fb[r][ bins[r] + jc*4 + d ]
    for (int i = gid; i < 9 * 256; i += gstr) {
        int jc = i >> 8, r = (i >> 2) & 63, d = i & 3;
        int j = jc * 4 + d;
        double v = 0.0;
        if (r < NMELS) {
            double flo = bins[r], fc = bins[r + 1], fhi = bins[r + 2];
            int k = (int)flo + j;
            if (k < (int)fc)        v = ((double)k - flo) / (fc - flo);
            else if (k < (int)fhi)  v = (fhi - (double)k) / (fhi - fc);
        }
        ws[WS_FBW + i] = (float)v;
    }

    // fused DCT + delta matrix, [n][i] layout: MT[n*39 + i]
    for (int t = gid; t < 40 * 39; t += gstr) {
        int n = t / 39, i = t % 39;
        auto dctf = [&](int c) -> double {
            if (c < 0 || c > 39) return 0.0;
            double sc = (c == 0) ? sqrt(1.0 / 40.0) : sqrt(2.0 / 40.0);
            return sc * cos(PI_D * (double)c * (2.0 * n + 1.0) / 80.0);
        };
        auto d1f = [&](int c) -> double {
            if (c < 1 || c > 38) return 0.0;
            return 0.5 * (dctf(c + 1) - dctf(c - 1));
        };
        double v;
        if (i < 13)       v = dctf(i);
        else if (i < 26)  v = d1f(i - 13);
        else { int c = i - 26; v = (c >= 1 && c <= 38) ? 0.5 * (d1f(c + 1) - d1f(c - 1)) : 0.0; }
        ws[WS_MT + t] = (float)v;
    }
}

// ---------------------------------------------------------------------------
// Main kernel: one WAVE per TWO adjacent frames (float2 SoA: .x=f0, .y=f1).
// Register FFT via shuffles; mel = gather (no atomics).
// ---------------------------------------------------------------------------
#define NTHREADS 256

__device__ __forceinline__ float2 shflx2(float2 v, int m) {
    return make_float2(__shfl_xor(v.x, m, 64), __shfl_xor(v.y, m, 64));
}
__device__ __forceinline__ float2 shfl2(float2 v, int src) {
    return make_float2(__shfl(v.x, src, 64), __shfl(v.y, src, 64));
}

__global__ __launch_bounds__(NTHREADS, 4) void mfcc_kernel(
    const float* __restrict__ x, const float* __restrict__ ws,
    float* __restrict__ out) {

    __shared__ float magA[4][2][304];               // padded mag, per wave/frame
    __shared__ __align__(16) float lm_all[4][2][44];

    const int tid = threadIdx.x;
    const int w = tid >> 6;
    const int l = tid & 63;
    const int gw = blockIdx.x * 4 + w;
    const int fid0 = 2 * gw;
    const int fid1 = fid0 + 1;
    const int b0 = fid0 / NF, f0 = fid0 - b0 * NF;
    const int b1 = fid1 / NF, f1 = fid1 - b1 * NF;
    const float* xp0 = x + (size_t)b0 * LL;
    const float* xp1 = x + (size_t)b1 * LL;
    const int st0 = f0 * HOP, st1 = f1 * HOP;

    // ---- prefetch shared tables ----
    const float2 w1  = *(const float2*)(ws + WS_W1 + 2 * l);
    const float2 tws0 = *(const float2*)(ws + WS_STW + 0 * 128 + 2 * l);
    const float2 tws1 = *(const float2*)(ws + WS_STW + 1 * 128 + 2 * l);
    const float2 tws2 = *(const float2*)(ws + WS_STW + 2 * 128 + 2 * l);
    const float2 tws3 = *(const float2*)(ws + WS_STW + 3 * 128 + 2 * l);
    const float2 tws4 = *(const float2*)(ws + WS_STW + 4 * 128 + 2 * l);

    // ---- pack both frames ----
    float2 z0r, z0i, z1r, z1i, z2r, z2i, z3r, z3i;
#define PACK(A, ZR, ZI)                                               \
    {                                                                 \
        float2 r = make_float2(0.f, 0.f), im = make_float2(0.f, 0.f); \
        int n2 = 2 * l + 128 * (A);                                   \
        if (n2 < WIN) {                                               \
            float2 wv = *(const float2*)(ws + WS_WINDOW + n2);        \
            int g0 = st0 + n2;                                        \
            float2 xv0 = *(const float2*)(xp0 + g0);                  \
            float xm0 = (g0 > 0) ? xp0[g0 - 1] : 0.0f;                \
            int g1 = st1 + n2;                                        \
            float2 xv1 = *(const float2*)(xp1 + g1);                  \
            float xm1 = (g1 > 0) ? xp1[g1 - 1] : 0.0f;                \
            r.x  = (xv0.x - 0.97f * xm0)   * wv.x;                    \
            im.x = (xv0.y - 0.97f * xv0.x) * wv.y;                    \
            r.y  = (xv1.x - 0.97f * xm1)   * wv.x;                    \
            im.y = (xv1.y - 0.97f * xv1.x) * wv.y;                    \
        }                                                             \
        ZR = r; ZI = im;                                              \
    }
    PACK(0, z0r, z0i)
    PACK(1, z1r, z1i)
    PACK(2, z2r, z2i)
    PACK(3, z3r, z3i)
#undef PACK

    // ---- in-register radix-4 over n1 (W4^1 = -i) ----
    {
        float2 t0r = make_float2(z0r.x + z2r.x, z0r.y + z2r.y);
        float2 t0i = make_float2(z0i.x + z2i.x, z0i.y + z2i.y);
        float2 t1r = make_float2(z0r.x - z2r.x, z0r.y - z2r.y);
        float2 t1i = make_float2(z0i.x - z2i.x, z0i.y - z2i.y);
        float2 t2r = make_float2(z1r.x + z3r.x, z1r.y + z3r.y);
        float2 t2i = make_float2(z1i.x + z3i.x, z1i.y + z3i.y);
        float2 t3r = make_float2(z1r.x - z3r.x, z1r.y - z3r.y);
        float2 t3i = make_float2(z1i.x - z3i.x, z1i.y - z3i.y);
        z0r = make_float2(t0r.x + t2r.x, t0r.y + t2r.y);
        z0i = make_float2(t0i.x + t2i.x, t0i.y + t2i.y);
        z1r = make_float2(t1r.x + t3i.x, t1r.y + t3i.y);
        z1i = make_float2(t1i.x - t3r.x, t1i.y - t3r.y);
        z2r = make_float2(t0r.x - t2r.x, t0r.y - t2r.y);
        z2i = make_float2(t0i.x - t2i.x, t0i.y - t2i.y);
        z3r = make_float2(t1r.x - t3i.x, t1r.y - t3i.y);
        z3i = make_float2(t1i.x + t3r.x, t1i.y + t3r.y);
    }

    // ---- twiddle by W_256^{l*k1} ----
#define CMULS(ZR, ZI, WR, WI)                                         \
    {                                                                 \
        float2 tr = make_float2(ZR.x * (WR) - ZI.x * (WI),            \
                                ZR.y * (WR) - ZI.y * (WI));           \
        ZI = make_float2(ZR.x * (WI) + ZI.x * (WR),                   \
                         ZR.y * (WI) + ZI.y * (WR));                  \
        ZR = tr;                                                      \
    }
    {
        float w2r = w1.x * w1.x - w1.y * w1.y, w2i = 2.0f * w1.x * w1.y;
        float w3r = w2r * w1.x - w2i * w1.y,   w3i = w2r * w1.y + w2i * w1.x;
        CMULS(z1r, z1i, w1.x, w1.y)
        CMULS(z2r, z2i, w2r,  w2i)
        CMULS(z3r, z3i, w3r,  w3i)
    }

    // ---- 6 cross-lane DIF stages via shfl_xor (output bit-reversed) ----
#define BFLY(ZR, ZI, H, TWR, TWI, SGN, LAST)                          \
    {                                                                 \
        float2 pr = shflx2(ZR, (H));                                  \
        float2 pi = shflx2(ZI, (H));                                  \
        float2 ar = make_float2(fmaf((SGN), ZR.x, pr.x),              \
                                fmaf((SGN), ZR.y, pr.y));             \
        float2 ai = make_float2(fmaf((SGN), ZI.x, pi.x),              \
                                fmaf((SGN), ZI.y, pi.y));             \
        if (LAST) { ZR = ar; ZI = ai; }                               \
        else {                                                        \
            ZR = make_float2(ar.x * (TWR) - ai.x * (TWI),             \
                             ar.y * (TWR) - ai.y * (TWI));            \
            ZI = make_float2(ar.x * (TWI) + ai.x * (TWR),             \
                             ar.y * (TWI) + ai.y * (TWR));            \
        }                                                             \
    }
#define CLSTAGE(H, TW, LAST)                                          \
    {                                                                 \
        float sgn = (l & (H)) ? -1.0f : 1.0f;                         \
        BFLY(z0r, z0i, H, TW.x, TW.y, sgn, LAST)                      \
        BFLY(z1r, z1i, H, TW.x, TW.y, sgn, LAST)                      \
        BFLY(z2r, z2i, H, TW.x, TW.y, sgn, LAST)                      \
        BFLY(z3r, z3i, H, TW.x, TW.y, sgn, LAST)                      \
    }
    CLSTAGE(32, tws0, false)
    CLSTAGE(16, tws1, false)
    CLSTAGE(8,  tws2, false)
    CLSTAGE(4,  tws3, false)
    CLSTAGE(2,  tws4, false)
    CLSTAGE(1,  tws4, true)
#undef CLSTAGE
#undef BFLY
#undef CMULS

    // lane l slot k1 holds Z[m], m = k1 + 4*bitrev6(l)

    // ---- rfft untangle ----
    float2 p1r = shflx2(z3r, 63), p1i = shflx2(z3i, 63);
    float2 p2r = shflx2(z2r, 63), p2i = shflx2(z2i, 63);
    float2 p3r = shflx2(z1r, 63), p3i = shflx2(z1i, 63);
    const int mrev = brev6(l);
    int q = brev6((64 - mrev) & 63);
    float2 p0r = shfl2(z0r, q), p0i = shfl2(z0i, q);

    float4 uc = *(const float4*)(ws + WS_UNTC + 4 * l);
    float4 us = *(const float4*)(ws + WS_UNTS + 4 * l);

    float2 mg0, mg1, mg2, mg3;
#define UNT(A, Bv, C, D, WR, WI, MG)                                  \
    {                                                                 \
        float2 Pr = make_float2(A.x + C.x, A.y + C.y);                \
        float2 Pi = make_float2(Bv.x - D.x, Bv.y - D.y);              \
        float2 Qr = make_float2(A.x - C.x, A.y - C.y);                \
        float2 Qi = make_float2(Bv.x + D.x, Bv.y + D.y);              \
        float Xr0 = 0.5f * (Pr.x + (WI) * Qr.x + (WR) * Qi.x);        \
        float Xi0 = 0.5f * (Pi.x + (WI) * Qi.x - (WR) * Qr.x);        \
        float Xr1 = 0.5f * (Pr.y + (WI) * Qr.y + (WR) * Qi.y);        \
        float Xi1 = 0.5f * (Pi.y + (WI) * Qi.y - (WR) * Qr.y);        \
        MG = make_float2(sqrtf(Xr0 * Xr0 + Xi0 * Xi0),                \
                         sqrtf(Xr1 * Xr1 + Xi1 * Xi1));               \
    }
    UNT(z0r, z0i, p0r, p0i, uc.x, us.x, mg0)
    UNT(z1r, z1i, p1r, p1i, uc.y, us.y, mg1)
    UNT(z2r, z2i, p2r, p2i, uc.z, us.z, mg2)
    UNT(z3r, z3i, p3r, p3i, uc.w, us.w, mg3)
#undef UNT

    // ---- store magnitudes to padded per-wave LDS (plain stores, no atomics) ----
    float* mf0 = magA[w][0];
    float* mf1 = magA[w][1];
    {
        int m0 = 0 + 4 * mrev, m1 = 1 + 4 * mrev, m2 = 2 + 4 * mrev, m3 = 3 + 4 * mrev;
        mf0[LOFF(m0)] = mg0.x;  mf1[LOFF(m0)] = mg0.y;
        mf0[LOFF(m1)] = mg1.x;  mf1[LOFF(m1)] = mg1.y;
        mf0[LOFF(m2)] = mg2.x;  mf1[LOFF(m2)] = mg2.y;
        mf0[LOFF(m3)] = mg3.x;  mf1[LOFF(m3)] = mg3.y;
    }
    if (l < 8) {                     // zero the overread tail (k >= 256 has w=0)
        int mm = 256 + l;
        mf0[LOFF(mm)] = 0.0f;
        mf1[LOFF(mm)] = 0.0f;
    }
    __builtin_amdgcn_wave_barrier();

    // ---- mel: lane l computes filter l (l<40) as dense dot over its support ----
    float2 mel = make_float2(0.f, 0.f);
    {
        int sm = (int)ws[WS_SM + l];
        #pragma unroll
        for (int jc = 0; jc < 9; jc++) {
            float4 fw = *(const float4*)(ws + WS_FBW + (jc * 64 + l) * 4);
            int bse = sm + jc * 4;
            mel.x = fmaf(fw.x, mf0[LOFF(bse + 0)], mel.x);
            mel.y = fmaf(fw.x, mf1[LOFF(bse + 0)], mel.y);
            mel.x = fmaf(fw.y, mf0[LOFF(bse + 1)], mel.x);
            mel.y = fmaf(fw.y, mf1[LOFF(bse + 1)], mel.y);
            mel.x = fmaf(fw.z, mf0[LOFF(bse + 2)], mel.x);
            mel.y = fmaf(fw.z, mf1[LOFF(bse + 2)], mel.y);
            mel.x = fmaf(fw.w, mf0[LOFF(bse + 3)], mel.x);
            mel.y = fmaf(fw.w, mf1[LOFF(bse + 3)], mel.y);
        }
    }

    // ---- log, stage lm into per-wave LDS for b128 broadcast ----
    float* lm0 = lm_all[w][0];
    float* lm1 = lm_all[w][1];
    if (l < NMELS) {
        lm0[l] = logf(mel.x + 1e-20f);
        lm1[l] = logf(mel.y + 1e-20f);
    }
    __builtin_amdgcn_wave_barrier();

    // ---- fused DCT+deltas matvec, both frames ----
    float2 acc = make_float2(0.f, 0.f);
    const float* mt = ws + WS_MT;
    int ii = (l < 39) ? l : 0;
    #pragma unroll
    for (int g = 0; g < 10; g++) {
        float4 a4 = *(const float4*)(lm0 + 4 * g);
        float4 b4 = *(const float4*)(lm1 + 4 * g);
        float m0 = mt[(4 * g + 0) * 39 + ii];
        float m1 = mt[(4 * g + 1) * 39 + ii];
        float m2 = mt[(4 * g + 2) * 39 + ii];
        float m3 = mt[(4 * g + 3) * 39 + ii];
        acc.x = fmaf(m0, a4.x, acc.x); acc.y = fmaf(m0, b4.x, acc.y);
        acc.x = fmaf(m1, a4.y, acc.x); acc.y = fmaf(m1, b4.y, acc.y);
        acc.x = fmaf(m2, a4.z, acc.x); acc.y = fmaf(m2, b4.z, acc.y);
        acc.x = fmaf(m3, a4.w, acc.x); acc.y = fmaf(m3, b4.w, acc.y);
    }
    if (l < 39) {
        out[(size_t)fid0 * 39 + l] = acc.x;
        out[(size_t)fid1 * 39 + l] = acc.y;
    }
}

// ---------------------------------------------------------------------------
extern "C" void kernel_launch(void* const* d_in, const int* in_sizes, int n_in,
                              void* d_out, int out_size, void* d_ws, size_t ws_size,
                              hipStream_t stream) {
    const float* x = (const float*)d_in[0];
    float* ws = (float*)d_ws;
    float* out = (float*)d_out;

    init_tables<<<8, 256, 0, stream>>>(ws);
    mfcc_kernel<<<(BB * NF) / 8, NTHREADS, 0, stream>>>(x, ws, out);
}

// Round 7
// 139.878 us; speedup vs baseline: 2.1465x; 1.0097x over previous
//
#include <hip/hip_runtime.h>
#include <cmath>

#define SRATE 16000
#define WIN   400
#define HOP   160
#define NFFT  512
#define NBIN  257          // NFFT/2+1
#define NMELS 40
#define NMFCC 13
#define BB    64
#define LL    160000
#define NF    998          // (L-WIN)/HOP + 1

#define PI_D 3.14159265358979323846

// workspace layout (floats)
#define WS_WINDOW 0                    // 400
#define WS_W1     400                  // 64 x float2 = 128   (W_256^l)
#define WS_STW    528                  // 6 stages x 64 x float2 = 768
#define WS_UNTC   1296                 // 64 x float4 = 256 (permuted untangle cos)
#define WS_UNTS   1552                 // 64 x float4 = 256 (permuted untangle -sin)
#define WS_SM     1808                 // 64 (filter support start bin)
#define WS_FBW    1872                 // 9 jc x 64 lanes x 4 = 2304 (mel weights)
#define WS_MTT    4176                 // 39 x 40 = 1560 (fused DCT+delta, TRANSPOSED [i][n])
#define WS_TOTAL  (WS_MTT + 1560)      // 5736 floats

__device__ __forceinline__ int brev6(int v) { return (int)(__brev((unsigned)v) >> 26); }

// ---------------------------------------------------------------------------
// Init kernel (64 blocks): recompute constant tables every launch.
// ---------------------------------------------------------------------------
__global__ void init_tables(float* __restrict__ ws) {
    __shared__ double bins[NMELS + 2];
    const int tid = threadIdx.x;
    const int gid = blockIdx.x * 256 + tid;
    const int gstr = gridDim.x * 256;

    // mel bin edges (every block computes its own copy)
    if (tid < NMELS + 2) {
        double high_mel = 2595.0 * log10(1.0 + ((double)SRATE / 2.0) / 700.0);
        double step = high_mel / (double)(NMELS + 1);
        double mel = (tid == NMELS + 1) ? high_mel : (double)tid * step;
        double hz = 700.0 * (pow(10.0, mel / 2595.0) - 1.0);
        bins[tid] = floor((double)(NFFT + 1) * hz / (double)SRATE);
    }
    __syncthreads();

    // Hamming window (periodic)
    for (int i = gid; i < WIN; i += gstr)
        ws[WS_WINDOW + i] = (float)(0.54 - 0.46 * cos(2.0 * PI_D * (double)i / (double)WIN));

    // W1[l] = e^{-2*pi*i*l/256}
    if (gid < 64) {
        double ang = -2.0 * PI_D * (double)gid / 256.0;
        ws[WS_W1 + 2 * gid]     = (float)cos(ang);
        ws[WS_W1 + 2 * gid + 1] = (float)sin(ang);
    }

    // cross-lane DIF stage twiddles
    for (int i = gid; i < 6 * 64; i += gstr) {
        int st = i >> 6, lane = i & 63;
        int h = 32 >> st;
        double cr = 1.0, ci = 0.0;
        if (lane & h) {
            double ang = -PI_D * (double)(lane & (h - 1)) / (double)h;
            cr = cos(ang); ci = sin(ang);
        }
        ws[WS_STW + st * 128 + 2 * lane]     = (float)cr;
        ws[WS_STW + st * 128 + 2 * lane + 1] = (float)ci;
    }

    // permuted untangle twiddles: lane l slot k1 -> m = k1 + 4*bitrev6(l)
    for (int i = gid; i < 256; i += gstr) {
        int lane = i >> 2, k1 = i & 3;
        int m = k1 + 4 * brev6(lane);
        double ang = 2.0 * PI_D * (double)m / 512.0;
        ws[WS_UNTC + 4 * lane + k1] = (float)cos(ang);
        ws[WS_UNTS + 4 * lane + k1] = (float)(-sin(ang));
    }

    // mel support start bins
    for (int i = gid; i < 64; i += gstr)
        ws[WS_SM + i] = (i < NMELS) ? (float)bins[i] : 0.0f;

    // mel weights, transposed for coalesced float4 loads:
    // FBW[jc*256 + r*4 + d] = fb[r][ bins[r] + jc*4 + d ]
    for (int i = gid; i < 9 * 256; i += gstr) {
        int jc = i >> 8, r = (i >> 2) & 63, d = i & 3;
        int j = jc * 4 + d;
        double v = 0.0;
        if (r < NMELS) {
            double flo = bins[r], fc = bins[r + 1], fhi = bins[r + 2];
            int k = (int)flo + j;
            if (k < (int)fc)        v = ((double)k - flo) / (fc - flo);
            else if (k < (int)fhi)  v = (fhi - (double)k) / (fhi - fc);
        }
        ws[WS_FBW + i] = (float)v;
    }

    // fused DCT + delta matrix, TRANSPOSED: MTT[i*40 + n] (row i contiguous in n)
    for (int t = gid; t < 39 * 40; t += gstr) {
        int i = t / 40, n = t % 40;
        auto dctf = [&](int c) -> double {
            if (c < 0 || c > 39) return 0.0;
            double sc = (c == 0) ? sqrt(1.0 / 40.0) : sqrt(2.0 / 40.0);
            return sc * cos(PI_D * (double)c * (2.0 * n + 1.0) / 80.0);
        };
        auto d1f = [&](int c) -> double {
            if (c < 1 || c > 38) return 0.0;
            return 0.5 * (dctf(c + 1) - dctf(c - 1));
        };
        double v;
        if (i < 13)       v = dctf(i);
        else if (i < 26)  v = d1f(i - 13);
        else { int c = i - 26; v = (c >= 1 && c <= 38) ? 0.5 * (d1f(c + 1) - d1f(c - 1)) : 0.0; }
        ws[WS_MTT + t] = (float)v;
    }
}

// ---------------------------------------------------------------------------
// Main kernel: one WAVE per TWO adjacent frames (float2 SoA: .x=f0, .y=f1).
// Register FFT via shuffles; mel = interleaved-LDS gather, no atomics.
// ---------------------------------------------------------------------------
#define NTHREADS 256

__device__ __forceinline__ float2 shflx2(float2 v, int m) {
    return make_float2(__shfl_xor(v.x, m, 64), __shfl_xor(v.y, m, 64));
}
__device__ __forceinline__ float2 shfl2(float2 v, int src) {
    return make_float2(__shfl(v.x, src, 64), __shfl(v.y, src, 64));
}

__global__ __launch_bounds__(NTHREADS, 4) void mfcc_kernel(
    const float* __restrict__ x, const float* __restrict__ ws,
    float* __restrict__ out) {

    // interleaved magnitudes: magI[w][2*m + frame], bins 0..263 (tail zeroed)
    __shared__ __align__(16) float magI[4][528];
    __shared__ __align__(16) float lm_all[4][2][44];

    const int tid = threadIdx.x;
    const int w = tid >> 6;
    const int l = tid & 63;
    const int gw = blockIdx.x * 4 + w;
    const int fid0 = 2 * gw;
    const int fid1 = fid0 + 1;
    const int b0 = fid0 / NF, f0 = fid0 - b0 * NF;
    const int b1 = fid1 / NF, f1 = fid1 - b1 * NF;
    const float* xp0 = x + (size_t)b0 * LL;
    const float* xp1 = x + (size_t)b1 * LL;
    const int st0 = f0 * HOP, st1 = f1 * HOP;

    // ---- prefetch shared tables ----
    const float2 w1  = *(const float2*)(ws + WS_W1 + 2 * l);
    const float2 tws0 = *(const float2*)(ws + WS_STW + 0 * 128 + 2 * l);
    const float2 tws1 = *(const float2*)(ws + WS_STW + 1 * 128 + 2 * l);
    const float2 tws2 = *(const float2*)(ws + WS_STW + 2 * 128 + 2 * l);
    const float2 tws3 = *(const float2*)(ws + WS_STW + 3 * 128 + 2 * l);
    const float2 tws4 = *(const float2*)(ws + WS_STW + 4 * 128 + 2 * l);
    const int sm2 = 2 * (int)ws[WS_SM + l];        // mel gather base (elements)

    // ---- pack both frames ----
    float2 z0r, z0i, z1r, z1i, z2r, z2i, z3r, z3i;
#define PACK(A, ZR, ZI)                                               \
    {                                                                 \
        float2 r = make_float2(0.f, 0.f), im = make_float2(0.f, 0.f); \
        int n2 = 2 * l + 128 * (A);                                   \
        if (n2 < WIN) {                                               \
            float2 wv = *(const float2*)(ws + WS_WINDOW + n2);        \
            int g0 = st0 + n2;                                        \
            float2 xv0 = *(const float2*)(xp0 + g0);                  \
            float xm0 = (g0 > 0) ? xp0[g0 - 1] : 0.0f;                \
            int g1 = st1 + n2;                                        \
            float2 xv1 = *(const float2*)(xp1 + g1);                  \
            float xm1 = (g1 > 0) ? xp1[g1 - 1] : 0.0f;                \
            r.x  = (xv0.x - 0.97f * xm0)   * wv.x;                    \
            im.x = (xv0.y - 0.97f * xv0.x) * wv.y;                    \
            r.y  = (xv1.x - 0.97f * xm1)   * wv.x;                    \
            im.y = (xv1.y - 0.97f * xv1.x) * wv.y;                    \
        }                                                             \
        ZR = r; ZI = im;                                              \
    }
    PACK(0, z0r, z0i)
    PACK(1, z1r, z1i)
    PACK(2, z2r, z2i)
    PACK(3, z3r, z3i)
#undef PACK

    // ---- in-register radix-4 over n1 (W4^1 = -i) ----
    {
        float2 t0r = make_float2(z0r.x + z2r.x, z0r.y + z2r.y);
        float2 t0i = make_float2(z0i.x + z2i.x, z0i.y + z2i.y);
        float2 t1r = make_float2(z0r.x - z2r.x, z0r.y - z2r.y);
        float2 t1i = make_float2(z0i.x - z2i.x, z0i.y - z2i.y);
        float2 t2r = make_float2(z1r.x + z3r.x, z1r.y + z3r.y);
        float2 t2i = make_float2(z1i.x + z3i.x, z1i.y + z3i.y);
        float2 t3r = make_float2(z1r.x - z3r.x, z1r.y - z3r.y);
        float2 t3i = make_float2(z1i.x - z3i.x, z1i.y - z3i.y);
        z0r = make_float2(t0r.x + t2r.x, t0r.y + t2r.y);
        z0i = make_float2(t0i.x + t2i.x, t0i.y + t2i.y);
        z1r = make_float2(t1r.x + t3i.x, t1r.y + t3i.y);
        z1i = make_float2(t1i.x - t3r.x, t1i.y - t3r.y);
        z2r = make_float2(t0r.x - t2r.x, t0r.y - t2r.y);
        z2i = make_float2(t0i.x - t2i.x, t0i.y - t2i.y);
        z3r = make_float2(t1r.x - t3i.x, t1r.y - t3i.y);
        z3i = make_float2(t1i.x + t3r.x, t1i.y + t3r.y);
    }

    // ---- twiddle by W_256^{l*k1} ----
#define CMULS(ZR, ZI, WR, WI)                                         \
    {                                                                 \
        float2 tr = make_float2(ZR.x * (WR) - ZI.x * (WI),            \
                                ZR.y * (WR) - ZI.y * (WI));           \
        ZI = make_float2(ZR.x * (WI) + ZI.x * (WR),                   \
                         ZR.y * (WI) + ZI.y * (WR));                  \
        ZR = tr;                                                      \
    }
    {
        float w2r = w1.x * w1.x - w1.y * w1.y, w2i = 2.0f * w1.x * w1.y;
        float w3r = w2r * w1.x - w2i * w1.y,   w3i = w2r * w1.y + w2i * w1.x;
        CMULS(z1r, z1i, w1.x, w1.y)
        CMULS(z2r, z2i, w2r,  w2i)
        CMULS(z3r, z3i, w3r,  w3i)
    }

    // ---- 6 cross-lane DIF stages via shfl_xor (output bit-reversed) ----
#define BFLY(ZR, ZI, H, TWR, TWI, SGN, LAST)                          \
    {                                                                 \
        float2 pr = shflx2(ZR, (H));                                  \
        float2 pi = shflx2(ZI, (H));                                  \
        float2 ar = make_float2(fmaf((SGN), ZR.x, pr.x),              \
                                fmaf((SGN), ZR.y, pr.y));             \
        float2 ai = make_float2(fmaf((SGN), ZI.x, pi.x),              \
                                fmaf((SGN), ZI.y, pi.y));             \
        if (LAST) { ZR = ar; ZI = ai; }                               \
        else {                                                        \
            ZR = make_float2(ar.x * (TWR) - ai.x * (TWI),             \
                             ar.y * (TWR) - ai.y * (TWI));            \
            ZI = make_float2(ar.x * (TWI) + ai.x * (TWR),             \
                             ar.y * (TWI) + ai.y * (TWR));            \
        }                                                             \
    }
#define CLSTAGE(H, TW, LAST)                                          \
    {                                                                 \
        float sgn = (l & (H)) ? -1.0f : 1.0f;                         \
        BFLY(z0r, z0i, H, TW.x, TW.y, sgn, LAST)                      \
        BFLY(z1r, z1i, H, TW.x, TW.y, sgn, LAST)                      \
        BFLY(z2r, z2i, H, TW.x, TW.y, sgn, LAST)                      \
        BFLY(z3r, z3i, H, TW.x, TW.y, sgn, LAST)                      \
    }
    CLSTAGE(32, tws0, false)
    CLSTAGE(16, tws1, false)
    CLSTAGE(8,  tws2, false)
    CLSTAGE(4,  tws3, false)
    CLSTAGE(2,  tws4, false)
    CLSTAGE(1,  tws4, true)
#undef CLSTAGE
#undef BFLY
#undef CMULS

    // lane l slot k1 holds Z[m], m = k1 + 4*bitrev6(l)

    // ---- rfft untangle ----
    float2 p1r = shflx2(z3r, 63), p1i = shflx2(z3i, 63);
    float2 p2r = shflx2(z2r, 63), p2i = shflx2(z2i, 63);
    float2 p3r = shflx2(z1r, 63), p3i = shflx2(z1i, 63);
    const int mrev = brev6(l);
    int q = brev6((64 - mrev) & 63);
    float2 p0r = shfl2(z0r, q), p0i = shfl2(z0i, q);

    float4 uc = *(const float4*)(ws + WS_UNTC + 4 * l);
    float4 us = *(const float4*)(ws + WS_UNTS + 4 * l);

    float2 mg0, mg1, mg2, mg3;
#define UNT(A, Bv, C, D, WR, WI, MG)                                  \
    {                                                                 \
        float2 Pr = make_float2(A.x + C.x, A.y + C.y);                \
        float2 Pi = make_float2(Bv.x - D.x, Bv.y - D.y);              \
        float2 Qr = make_float2(A.x - C.x, A.y - C.y);                \
        float2 Qi = make_float2(Bv.x + D.x, Bv.y + D.y);              \
        float Xr0 = 0.5f * (Pr.x + (WI) * Qr.x + (WR) * Qi.x);        \
        float Xi0 = 0.5f * (Pi.x + (WI) * Qi.x - (WR) * Qr.x);        \
        float Xr1 = 0.5f * (Pr.y + (WI) * Qr.y + (WR) * Qi.y);        \
        float Xi1 = 0.5f * (Pi.y + (WI) * Qi.y - (WR) * Qr.y);        \
        MG = make_float2(sqrtf(Xr0 * Xr0 + Xi0 * Xi0),                \
                         sqrtf(Xr1 * Xr1 + Xi1 * Xi1));               \
    }
    UNT(z0r, z0i, p0r, p0i, uc.x, us.x, mg0)
    UNT(z1r, z1i, p1r, p1i, uc.y, us.y, mg1)
    UNT(z2r, z2i, p2r, p2i, uc.z, us.z, mg2)
    UNT(z3r, z3i, p3r, p3i, uc.w, us.w, mg3)
#undef UNT

    // ---- store magnitudes interleaved: idx 2m+frame; slots k1=0..3 are 8
    //      consecutive floats at 8*mrev -> two b128 stores ----
    float* mw = magI[w];
    {
        float4 s0 = make_float4(mg0.x, mg0.y, mg1.x, mg1.y);
        float4 s1 = make_float4(mg2.x, mg2.y, mg3.x, mg3.y);
        *(float4*)(mw + 8 * mrev)     = s0;
        *(float4*)(mw + 8 * mrev + 4) = s1;
    }
    if (l < 4) {   // zero tail bins 256..263 (overread region, weights are 0)
        *(float2*)(mw + 512 + 4 * l) = make_float2(0.f, 0.f);
        *(float2*)(mw + 512 + 4 * l + 2) = make_float2(0.f, 0.f);
    }
    __builtin_amdgcn_wave_barrier();

    // ---- mel: lane l = filter l; 36 x ds_read_b64 (both frames) with
    //      immediate offsets off one base ----
    float2 mel = make_float2(0.f, 0.f);
    {
        const float* mbase = mw + sm2;
        #pragma unroll
        for (int jc = 0; jc < 9; jc++) {
            float4 fw = *(const float4*)(ws + WS_FBW + (jc * 64 + l) * 4);
            float2 ma = *(const float2*)(mbase + 2 * (4 * jc + 0));
            float2 mb = *(const float2*)(mbase + 2 * (4 * jc + 1));
            float2 mc = *(const float2*)(mbase + 2 * (4 * jc + 2));
            float2 md = *(const float2*)(mbase + 2 * (4 * jc + 3));
            mel.x = fmaf(fw.x, ma.x, mel.x);  mel.y = fmaf(fw.x, ma.y, mel.y);
            mel.x = fmaf(fw.y, mb.x, mel.x);  mel.y = fmaf(fw.y, mb.y, mel.y);
            mel.x = fmaf(fw.z, mc.x, mel.x);  mel.y = fmaf(fw.z, mc.y, mel.y);
            mel.x = fmaf(fw.w, md.x, mel.x);  mel.y = fmaf(fw.w, md.y, mel.y);
        }
    }

    // ---- log, stage lm into per-wave LDS for b128 broadcast ----
    float* lm0 = lm_all[w][0];
    float* lm1 = lm_all[w][1];
    if (l < NMELS) {
        lm0[l] = logf(mel.x + 1e-20f);
        lm1[l] = logf(mel.y + 1e-20f);
    }
    __builtin_amdgcn_wave_barrier();

    // ---- fused DCT+deltas matvec: MTT row i contiguous -> 10 b128 loads ----
    float2 acc = make_float2(0.f, 0.f);
    int ii = (l < 39) ? l : 0;
    const float* mrow = ws + WS_MTT + ii * 40;
    #pragma unroll
    for (int g = 0; g < 10; g++) {
        float4 m4 = *(const float4*)(mrow + 4 * g);
        float4 a4 = *(const float4*)(lm0 + 4 * g);
        float4 b4 = *(const float4*)(lm1 + 4 * g);
        acc.x = fmaf(m4.x, a4.x, acc.x); acc.y = fmaf(m4.x, b4.x, acc.y);
        acc.x = fmaf(m4.y, a4.y, acc.x); acc.y = fmaf(m4.y, b4.y, acc.y);
        acc.x = fmaf(m4.z, a4.z, acc.x); acc.y = fmaf(m4.z, b4.z, acc.y);
        acc.x = fmaf(m4.w, a4.w, acc.x); acc.y = fmaf(m4.w, b4.w, acc.y);
    }
    if (l < 39) {
        out[(size_t)fid0 * 39 + l] = acc.x;
        out[(size_t)fid1 * 39 + l] = acc.y;
    }
}

// ---------------------------------------------------------------------------
extern "C" void kernel_launch(void* const* d_in, const int* in_sizes, int n_in,
                              void* d_out, int out_size, void* d_ws, size_t ws_size,
                              hipStream_t stream) {
    const float* x = (const float*)d_in[0];
    float* ws = (float*)d_ws;
    float* out = (float*)d_out;

    init_tables<<<64, 256, 0, stream>>>(ws);
    mfcc_kernel<<<(BB * NF) / 8, NTHREADS, 0, stream>>>(x, ws, out);
}

// Round 8
// 128.634 us; speedup vs baseline: 2.3341x; 1.0874x over previous
//
#include <hip/hip_runtime.h>
#include <cmath>

#define SRATE 16000
#define WIN   400
#define HOP   160
#define NFFT  512
#define NBIN  257          // NFFT/2+1
#define NMELS 40
#define NMFCC 13
#define BB    64
#define LL    160000
#define NF    998          // (L-WIN)/HOP + 1

#define PI_D 3.14159265358979323846

// workspace layout (floats)
#define WS_WINDOW 0                    // 400
#define WS_W1     400                  // 64 x float2 = 128   (W_256^l)
#define WS_STW    528                  // 6 stages x 64 x float2 = 768
#define WS_UNTC   1296                 // 64 x float4 = 256 (permuted untangle cos)
#define WS_UNTS   1552                 // 64 x float4 = 256 (permuted untangle -sin)
#define WS_SM     1808                 // 64 (filter support start bin)
#define WS_FBW    1872                 // 9 jc x 64 lanes x 4 = 2304 (mel weights)
#define WS_MTT    4176                 // 39 x 40 = 1560 (fused DCT+delta, TRANSPOSED [i][n])
#define WS_TOTAL  (WS_MTT + 1560)      // 5736 floats

using v2f = __attribute__((ext_vector_type(2))) float;

__device__ __forceinline__ int brev6(int v) { return (int)(__brev((unsigned)v) >> 26); }
__device__ __forceinline__ v2f splat(float s) { v2f r; r.x = s; r.y = s; return r; }

template<int CTRL>
__device__ __forceinline__ float dppf(float x) {
    return __int_as_float(__builtin_amdgcn_mov_dpp(__float_as_int(x), CTRL, 0xF, 0xF, true));
}
template<int CTRL>
__device__ __forceinline__ v2f dpp2(v2f v) {
    v2f r; r.x = dppf<CTRL>(v.x); r.y = dppf<CTRL>(v.y); return r;
}
__device__ __forceinline__ v2f sfx2(v2f v, int m) {
    v2f r; r.x = __shfl_xor(v.x, m, 64); r.y = __shfl_xor(v.y, m, 64); return r;
}
__device__ __forceinline__ v2f sfl2(v2f v, int src) {
    v2f r; r.x = __shfl(v.x, src, 64); r.y = __shfl(v.y, src, 64); return r;
}

// DPP controls: quad_perm xor1 = [1,0,3,2] = 0xB1; xor2 = [2,3,0,1] = 0x4E;
// row_ror:8 = 0x128 (== xor8 within each 16-lane row).
#define DPP_XOR1 0xB1
#define DPP_XOR2 0x4E
#define DPP_XOR8 0x128

// ---------------------------------------------------------------------------
// Init kernel (64 blocks): recompute constant tables every launch.
// ---------------------------------------------------------------------------
__global__ void init_tables(float* __restrict__ ws) {
    __shared__ double bins[NMELS + 2];
    const int tid = threadIdx.x;
    const int gid = blockIdx.x * 256 + tid;
    const int gstr = gridDim.x * 256;

    if (tid < NMELS + 2) {
        double high_mel = 2595.0 * log10(1.0 + ((double)SRATE / 2.0) / 700.0);
        double step = high_mel / (double)(NMELS + 1);
        double mel = (tid == NMELS + 1) ? high_mel : (double)tid * step;
        double hz = 700.0 * (pow(10.0, mel / 2595.0) - 1.0);
        bins[tid] = floor((double)(NFFT + 1) * hz / (double)SRATE);
    }
    __syncthreads();

    for (int i = gid; i < WIN; i += gstr)
        ws[WS_WINDOW + i] = (float)(0.54 - 0.46 * cos(2.0 * PI_D * (double)i / (double)WIN));

    if (gid < 64) {
        double ang = -2.0 * PI_D * (double)gid / 256.0;
        ws[WS_W1 + 2 * gid]     = (float)cos(ang);
        ws[WS_W1 + 2 * gid + 1] = (float)sin(ang);
    }

    for (int i = gid; i < 6 * 64; i += gstr) {
        int st = i >> 6, lane = i & 63;
        int h = 32 >> st;
        double cr = 1.0, ci = 0.0;
        if (lane & h) {
            double ang = -PI_D * (double)(lane & (h - 1)) / (double)h;
            cr = cos(ang); ci = sin(ang);
        }
        ws[WS_STW + st * 128 + 2 * lane]     = (float)cr;
        ws[WS_STW + st * 128 + 2 * lane + 1] = (float)ci;
    }

    for (int i = gid; i < 256; i += gstr) {
        int lane = i >> 2, k1 = i & 3;
        int m = k1 + 4 * brev6(lane);
        double ang = 2.0 * PI_D * (double)m / 512.0;
        ws[WS_UNTC + 4 * lane + k1] = (float)cos(ang);
        ws[WS_UNTS + 4 * lane + k1] = (float)(-sin(ang));
    }

    for (int i = gid; i < 64; i += gstr)
        ws[WS_SM + i] = (i < NMELS) ? (float)bins[i] : 0.0f;

    for (int i = gid; i < 9 * 256; i += gstr) {
        int jc = i >> 8, r = (i >> 2) & 63, d = i & 3;
        int j = jc * 4 + d;
        double v = 0.0;
        if (r < NMELS) {
            double flo = bins[r], fc = bins[r + 1], fhi = bins[r + 2];
            int k = (int)flo + j;
            if (k < (int)fc)        v = ((double)k - flo) / (fc - flo);
            else if (k < (int)fhi)  v = (fhi - (double)k) / (fhi - fc);
        }
        ws[WS_FBW + i] = (float)v;
    }

    for (int t = gid; t < 39 * 40; t += gstr) {
        int i = t / 40, n = t % 40;
        auto dctf = [&](int c) -> double {
            if (c < 0 || c > 39) return 0.0;
            double sc = (c == 0) ? sqrt(1.0 / 40.0) : sqrt(2.0 / 40.0);
            return sc * cos(PI_D * (double)c * (2.0 * n + 1.0) / 80.0);
        };
        auto d1f = [&](int c) -> double {
            if (c < 1 || c > 38) return 0.0;
            return 0.5 * (dctf(c + 1) - dctf(c - 1));
        };
        double v;
        if (i < 13)       v = dctf(i);
        else if (i < 26)  v = d1f(i - 13);
        else { int c = i - 26; v = (c >= 1 && c <= 38) ? 0.5 * (d1f(c + 1) - d1f(c - 1)) : 0.0; }
        ws[WS_MTT + t] = (float)v;
    }
}

// ---------------------------------------------------------------------------
// Main kernel: one WAVE per TWO adjacent frames, v2f packed math (v_pk_fma),
// DPP shuffles for xor 1/2/8, DS shuffles only for xor 4/16/32.
// ---------------------------------------------------------------------------
#define NTHREADS 256

__global__ __launch_bounds__(NTHREADS, 6) void mfcc_kernel(
    const float* __restrict__ x, const float* __restrict__ ws,
    float* __restrict__ out) {

    __shared__ __align__(16) float magI[4][528];   // interleaved mag: [2m+frame]
    __shared__ __align__(16) float lmI[4][88];     // interleaved log-mel

    const int tid = threadIdx.x;
    const int w = tid >> 6;
    const int l = tid & 63;
    const int gw = blockIdx.x * 4 + w;
    const int fid0 = 2 * gw;
    const int fid1 = fid0 + 1;
    const int b0 = fid0 / NF, f0 = fid0 - b0 * NF;
    const int b1 = fid1 / NF, f1 = fid1 - b1 * NF;
    const float* xp0 = x + (size_t)b0 * LL;
    const float* xp1 = x + (size_t)b1 * LL;
    const int st0 = f0 * HOP, st1 = f1 * HOP;

    // ---- prefetch shared tables ----
    const float2 w1   = *(const float2*)(ws + WS_W1 + 2 * l);
    const float2 tws0 = *(const float2*)(ws + WS_STW + 0 * 128 + 2 * l);
    const float2 tws1 = *(const float2*)(ws + WS_STW + 1 * 128 + 2 * l);
    const float2 tws2 = *(const float2*)(ws + WS_STW + 2 * 128 + 2 * l);
    const float2 tws3 = *(const float2*)(ws + WS_STW + 3 * 128 + 2 * l);
    const float2 tws4 = *(const float2*)(ws + WS_STW + 4 * 128 + 2 * l);
    const int sm2 = 2 * (int)ws[WS_SM + l];

    // ---- pack both frames: lane l slot a holds z[l + 64a] ----
    v2f z0r, z0i, z1r, z1i, z2r, z2i, z3r, z3i;
#define PACK(A, ZR, ZI)                                               \
    {                                                                 \
        v2f r = splat(0.f), im = splat(0.f);                          \
        int n2 = 2 * l + 128 * (A);                                   \
        if (n2 < WIN) {                                               \
            float2 wv = *(const float2*)(ws + WS_WINDOW + n2);        \
            int g0 = st0 + n2;                                        \
            float2 xv0 = *(const float2*)(xp0 + g0);                  \
            float xm0 = (g0 > 0) ? xp0[g0 - 1] : 0.0f;                \
            int g1 = st1 + n2;                                        \
            float2 xv1 = *(const float2*)(xp1 + g1);                  \
            float xm1 = (g1 > 0) ? xp1[g1 - 1] : 0.0f;                \
            r.x  = (xv0.x - 0.97f * xm0)   * wv.x;                    \
            im.x = (xv0.y - 0.97f * xv0.x) * wv.y;                    \
            r.y  = (xv1.x - 0.97f * xm1)   * wv.x;                    \
            im.y = (xv1.y - 0.97f * xv1.x) * wv.y;                    \
        }                                                             \
        ZR = r; ZI = im;                                              \
    }
    PACK(0, z0r, z0i)
    PACK(1, z1r, z1i)
    PACK(2, z2r, z2i)
    PACK(3, z3r, z3i)
#undef PACK

    // ---- in-register radix-4 over n1 (W4^1 = -i), packed ----
    {
        v2f t0r = z0r + z2r, t0i = z0i + z2i;
        v2f t1r = z0r - z2r, t1i = z0i - z2i;
        v2f t2r = z1r + z3r, t2i = z1i + z3i;
        v2f t3r = z1r - z3r, t3i = z1i - z3i;
        z0r = t0r + t2r;  z0i = t0i + t2i;
        z1r = t1r + t3i;  z1i = t1i - t3r;
        z2r = t0r - t2r;  z2i = t0i - t2i;
        z3r = t1r - t3i;  z3i = t1i + t3r;
    }

    // ---- twiddle by W_256^{l*k1}, packed ----
#define CMUL(ZR, ZI, WR, WI)                                          \
    {                                                                 \
        v2f wr = splat(WR), wi = splat(WI);                           \
        v2f tr = ZR * wr - ZI * wi;                                   \
        ZI = ZR * wi + ZI * wr;                                       \
        ZR = tr;                                                      \
    }
    {
        float w2r = w1.x * w1.x - w1.y * w1.y, w2i = 2.0f * w1.x * w1.y;
        float w3r = w2r * w1.x - w2i * w1.y,   w3i = w2r * w1.y + w2i * w1.x;
        CMUL(z1r, z1i, w1.x, w1.y)
        CMUL(z2r, z2i, w2r,  w2i)
        CMUL(z3r, z3i, w3r,  w3i)
    }
#undef CMUL

    // ---- 6 cross-lane DIF stages (xor 32/16/4 via DS, xor 8/2/1 via DPP) ----
#define BFLY_CORE(ZR, ZI, PR, PI, TWR, TWI, SG, LAST)                 \
    {                                                                 \
        v2f ar = __builtin_elementwise_fma(SG, ZR, PR);               \
        v2f ai = __builtin_elementwise_fma(SG, ZI, PI);               \
        if (LAST) { ZR = ar; ZI = ai; }                               \
        else { ZR = ar * TWR - ai * TWI;                              \
               ZI = ar * TWI + ai * TWR; }                            \
    }
#define STAGE_X(H, TW)                                                \
    {                                                                 \
        v2f sg = splat((l & (H)) ? -1.0f : 1.0f);                     \
        v2f twr = splat(TW.x), twi = splat(TW.y);                     \
        { v2f pr = sfx2(z0r, H), pi = sfx2(z0i, H);                   \
          BFLY_CORE(z0r, z0i, pr, pi, twr, twi, sg, false) }          \
        { v2f pr = sfx2(z1r, H), pi = sfx2(z1i, H);                   \
          BFLY_CORE(z1r, z1i, pr, pi, twr, twi, sg, false) }          \
        { v2f pr = sfx2(z2r, H), pi = sfx2(z2i, H);                   \
          BFLY_CORE(z2r, z2i, pr, pi, twr, twi, sg, false) }          \
        { v2f pr = sfx2(z3r, H), pi = sfx2(z3i, H);                   \
          BFLY_CORE(z3r, z3i, pr, pi, twr, twi, sg, false) }          \
    }
#define STAGE_D(H, CTRL, TW, LAST)                                    \
    {                                                                 \
        v2f sg = splat((l & (H)) ? -1.0f : 1.0f);                     \
        v2f twr = splat(TW.x), twi = splat(TW.y);                     \
        { v2f pr = dpp2<CTRL>(z0r), pi = dpp2<CTRL>(z0i);             \
          BFLY_CORE(z0r, z0i, pr, pi, twr, twi, sg, LAST) }           \
        { v2f pr = dpp2<CTRL>(z1r), pi = dpp2<CTRL>(z1i);             \
          BFLY_CORE(z1r, z1i, pr, pi, twr, twi, sg, LAST) }           \
        { v2f pr = dpp2<CTRL>(z2r), pi = dpp2<CTRL>(z2i);             \
          BFLY_CORE(z2r, z2i, pr, pi, twr, twi, sg, LAST) }           \
        { v2f pr = dpp2<CTRL>(z3r), pi = dpp2<CTRL>(z3i);             \
          BFLY_CORE(z3r, z3i, pr, pi, twr, twi, sg, LAST) }           \
    }
    STAGE_X(32, tws0)
    STAGE_X(16, tws1)
    STAGE_D(8,  DPP_XOR8, tws2, false)
    STAGE_X(4,  tws3)
    STAGE_D(2,  DPP_XOR2, tws4, false)
    STAGE_D(1,  DPP_XOR1, tws4, true)     // last: twiddle unused
#undef STAGE_X
#undef STAGE_D
#undef BFLY_CORE

    // lane l slot k1 holds Z[m], m = k1 + 4*bitrev6(l)

    // ---- rfft untangle ----
    v2f p1r = sfx2(z3r, 63), p1i = sfx2(z3i, 63);
    v2f p2r = sfx2(z2r, 63), p2i = sfx2(z2i, 63);
    v2f p3r = sfx2(z1r, 63), p3i = sfx2(z1i, 63);
    const int mrev = brev6(l);
    int q = brev6((64 - mrev) & 63);
    v2f p0r = sfl2(z0r, q), p0i = sfl2(z0i, q);

    float4 uc = *(const float4*)(ws + WS_UNTC + 4 * l);
    float4 us = *(const float4*)(ws + WS_UNTS + 4 * l);

    v2f mg0, mg1, mg2, mg3;
#define UNT(A, Bv, C, D, WR, WI, MG)                                  \
    {                                                                 \
        v2f Pr = A + C, Pi = Bv - D;                                  \
        v2f Qr = A - C, Qi = Bv + D;                                  \
        v2f wr = splat(WR), wi = splat(WI);                           \
        v2f Xr = splat(0.5f) * (Pr + wi * Qr + wr * Qi);              \
        v2f Xi = splat(0.5f) * (Pi + wi * Qi - wr * Qr);              \
        v2f s2 = __builtin_elementwise_fma(Xr, Xr, Xi * Xi);          \
        MG.x = sqrtf(s2.x); MG.y = sqrtf(s2.y);                       \
    }
    UNT(z0r, z0i, p0r, p0i, uc.x, us.x, mg0)
    UNT(z1r, z1i, p1r, p1i, uc.y, us.y, mg1)
    UNT(z2r, z2i, p2r, p2i, uc.z, us.z, mg2)
    UNT(z3r, z3i, p3r, p3i, uc.w, us.w, mg3)
#undef UNT

    // ---- store magnitudes interleaved: two b128 stores ----
    float* mw = magI[w];
    {
        float4 s0 = make_float4(mg0.x, mg0.y, mg1.x, mg1.y);
        float4 s1 = make_float4(mg2.x, mg2.y, mg3.x, mg3.y);
        *(float4*)(mw + 8 * mrev)     = s0;
        *(float4*)(mw + 8 * mrev + 4) = s1;
    }
    if (l < 4) {   // zero tail bins 256..263 (overread region, weights are 0)
        *(float4*)(mw + 512 + 4 * l) = make_float4(0.f, 0.f, 0.f, 0.f);
    }
    __builtin_amdgcn_wave_barrier();

    // ---- mel: lane l = filter l; 36 b64 reads, packed FMA ----
    v2f mel = splat(0.f);
    {
        const float* mbase = mw + sm2;
        #pragma unroll
        for (int jc = 0; jc < 9; jc++) {
            float4 fw = *(const float4*)(ws + WS_FBW + (jc * 64 + l) * 4);
            v2f ma = *(const v2f*)(mbase + 8 * jc + 0);
            v2f mb = *(const v2f*)(mbase + 8 * jc + 2);
            v2f mc = *(const v2f*)(mbase + 8 * jc + 4);
            v2f md = *(const v2f*)(mbase + 8 * jc + 6);
            mel = __builtin_elementwise_fma(splat(fw.x), ma, mel);
            mel = __builtin_elementwise_fma(splat(fw.y), mb, mel);
            mel = __builtin_elementwise_fma(splat(fw.z), mc, mel);
            mel = __builtin_elementwise_fma(splat(fw.w), md, mel);
        }
    }

    // ---- log, stage interleaved lm (one b64 write) ----
    float* lmi = lmI[w];
    if (l < NMELS) {
        v2f lg;
        lg.x = logf(mel.x + 1e-20f);
        lg.y = logf(mel.y + 1e-20f);
        *(v2f*)(lmi + 2 * l) = lg;
    }
    __builtin_amdgcn_wave_barrier();

    // ---- fused DCT+deltas matvec: b128 broadcast reads give packed pairs ----
    v2f acc = splat(0.f);
    int ii = (l < 39) ? l : 0;
    const float* mrow = ws + WS_MTT + ii * 40;
    #pragma unroll
    for (int g = 0; g < 10; g++) {
        float4 m4 = *(const float4*)(mrow + 4 * g);
        float4 q0 = *(const float4*)(lmi + 8 * g);
        float4 q1 = *(const float4*)(lmi + 8 * g + 4);
        v2f p0; p0.x = q0.x; p0.y = q0.y;
        v2f p1; p1.x = q0.z; p1.y = q0.w;
        v2f p2; p2.x = q1.x; p2.y = q1.y;
        v2f p3; p3.x = q1.z; p3.y = q1.w;
        acc = __builtin_elementwise_fma(splat(m4.x), p0, acc);
        acc = __builtin_elementwise_fma(splat(m4.y), p1, acc);
        acc = __builtin_elementwise_fma(splat(m4.z), p2, acc);
        acc = __builtin_elementwise_fma(splat(m4.w), p3, acc);
    }
    if (l < 39) {
        out[(size_t)fid0 * 39 + l] = acc.x;
        out[(size_t)fid1 * 39 + l] = acc.y;
    }
}

// ---------------------------------------------------------------------------
extern "C" void kernel_launch(void* const* d_in, const int* in_sizes, int n_in,
                              void* d_out, int out_size, void* d_ws, size_t ws_size,
                              hipStream_t stream) {
    const float* x = (const float*)d_in[0];
    float* ws = (float*)d_ws;
    float* out = (float*)d_out;

    init_tables<<<64, 256, 0, stream>>>(ws);
    mfcc_kernel<<<(BB * NF) / 8, NTHREADS, 0, stream>>>(x, ws, out);
}